// Round 11
// baseline (61256.482 us; speedup 1.0000x reference)
//
#include <hip/hip_runtime.h>
#include <math.h>

#define NT  256
#define NWG 64
#define SCOPE_AG __HIP_MEMORY_SCOPE_AGENT
typedef unsigned long long ull;

// ---------- agent-scope (coherence-point) atomic helpers ----------
__device__ __forceinline__ float ld_f(const float* p) {
    return __hip_atomic_load(p, __ATOMIC_RELAXED, SCOPE_AG);
}
__device__ __forceinline__ void st_f(float* p, float v) {
    __hip_atomic_store(p, v, __ATOMIC_RELAXED, SCOPE_AG);
}
__device__ __forceinline__ unsigned ld_u(const unsigned* p) {
    return __hip_atomic_load(p, __ATOMIC_RELAXED, SCOPE_AG);
}
__device__ __forceinline__ void st_u(unsigned* p, unsigned v) {
    __hip_atomic_store(p, v, __ATOMIC_RELAXED, SCOPE_AG);
}
__device__ __forceinline__ ull ld_u64(const ull* p) {
    return __hip_atomic_load(p, __ATOMIC_RELAXED, SCOPE_AG);
}
__device__ __forceinline__ void st_u64(ull* p, ull v) {
    __hip_atomic_store(p, v, __ATOMIC_RELAXED, SCOPE_AG);
}
__device__ __forceinline__ ull pack_tf(unsigned tag, float v) {
    return ((ull)__float_as_uint(v) << 32) | (ull)tag;
}
__device__ __forceinline__ float hi_f(ull u) { return __uint_as_float((unsigned)(u >> 32)); }

// bf16 pack/unpack via bit ops (round-to-nearest-even). even value -> low16.
__device__ __forceinline__ unsigned bf16pack(float even, float odd) {
    unsigned ua = __float_as_uint(even); ua += 0x7FFFu + ((ua >> 16) & 1u);
    unsigned ub = __float_as_uint(odd);  ub += 0x7FFFu + ((ub >> 16) & 1u);
    return (ua >> 16) | (ub & 0xFFFF0000u);
}
__device__ __forceinline__ float bf16lo(unsigned w) { return __uint_as_float(w << 16); }
__device__ __forceinline__ float bf16hi(unsigned w) { return __uint_as_float(w & 0xFFFF0000u); }

__device__ __forceinline__ float wsum64(float v) {
    #pragma unroll
    for (int m = 1; m < 64; m <<= 1) v += __shfl_xor(v, m);
    return v;
}
__device__ __forceinline__ float wmax64(float v) {
    #pragma unroll
    for (int m = 1; m < 64; m <<= 1) v = fmaxf(v, __shfl_xor(v, m));
    return v;
}

// ws layout (floats) — total 164,928 floats = 659,712 B (well under proven bound):
//   partuw: ull[2 par][512 (b,w)][8 c][2 re/im]  @ 0        (32768 floats)
//           word = (float_bits<<32) | stag,  stag = iter*512+blk+1
//   tau32:  unsigned[512 blk][8 b][32 w-pairs]   @ 32768    (131072 floats; bf16x2)
//   pmws:   float[64]                            @ 163840
//   flags:  unsigned[2 plane][64 wg][8 stride]   @ 163904 .. 164928
//
// Tag protocol: consumers poll each partial word for tag == stag (equality).
// 2-parity buffering guarantees no clobber-while-polled (bounded lead).
// Replay-safe: first polls use stag 1/2; stale words hold 5119/5120 or the
// init clear's 0 — never equal. Iteration-boundary barrier: ping-pong
// equality flags (R10-proven).

__launch_bounds__(NT, 1)
__global__ void robii_kernel(
    const float* __restrict__ y_re, const float* __restrict__ y_im,
    const float* __restrict__ H_re, const float* __restrict__ H_im,
    const float* __restrict__ estep_w, const float* __restrict__ estep_b,
    const float* __restrict__ update_w, const float* __restrict__ update_b,
    const float* __restrict__ memory_w, const float* __restrict__ memory_b,
    float* __restrict__ out, float* __restrict__ ws)
{
    __shared__ float wTe[4096], wTu[4096], wTm[4096];  // transposed: wT[k*64+j] = w[j][k]
    __shared__ float be[64], bu[64], bm[64];
    __shared__ float a2s[512];
    __shared__ float redl[8];
    __shared__ float gmax[1];
    __shared__ float2 rown[64];
    __shared__ float xts[64], hts[64], taurow[64];
    __shared__ float2 resid[64];
    __shared__ float2 cpartC[4][32][4];   // Phase-C scratch; aliased as MLP partials
    __shared__ float2 x_l[128];     // this WG's x[b, c*128 .. c*128+127]

    float* mpartf = (float*)cpartC;  // [4][64] floats (time-shared with Phase C)

    const int g = blockIdx.x, t = threadIdx.x;
    const int c = g & 7;        // d-chunk owned
    const int b = g >> 3;       // batch owned
    const int lane = t & 63, wv = t >> 6;
    const int sub = t & 31;     // column slice (4 floats)
    const int rbase = t >> 5;   // row group 0..7 (rows rbase+8j)

    ull*      partuw = (ull*)ws;                    // [2*512*8*2]
    unsigned* tau32  = (unsigned*)(ws + 32768);     // [512*8*32]
    float*    pmws   = ws + 163840;                 // [64]
    unsigned* flags  = (unsigned*)(ws + 163904);    // [2][64][8]

    // ---------------- init ----------------
    for (int i = t; i < 4096; i += NT) {
        int j = i >> 6, k = i & 63;
        wTe[k * 64 + j] = estep_w[i];
        wTu[k * 64 + j] = update_w[i];
        wTm[k * 64 + j] = memory_w[i];
    }
    if (t < 64) { be[t] = estep_b[t]; bu[t] = update_b[t]; bm[t] = memory_b[t]; taurow[t] = 1.0f; }
    if (t < 128) x_l[t] = make_float2(0.0f, 0.0f);
    for (int i = t; i < 2048; i += NT) st_u(&tau32[g * 2048 + i], 0x3F803F80u);  // bf16x2(1,1)
    {   // clear own partial words (2 par x 64 w x 2 re/im = 256 words, 1/thread)
        int par_i = t >> 7, w_i = (t >> 1) & 63, reim = t & 1;
        st_u64(&partuw[((size_t)par_i * 512 + b * 64 + w_i) * 16 + (size_t)c * 2 + reim], 0ull);
    }

    unsigned ep = 1;
    // init barrier (ep=1, plane 1): publishes tau init + partial clears.
    {
        unsigned* plane = flags + ((ep & 1u) << 9);
        __syncthreads();
        if (t == 0) st_u(&plane[g * 8], ep);
        if (t < 64) {
            while (ld_u(&plane[t * 8]) != ep) __builtin_amdgcn_s_sleep(1);
        }
        __syncthreads();
    }

    const size_t hcol = (size_t)c * 128 + (size_t)sub * 4;

    // H double-buffer register banks
    float4 hAre[8], hAim[8], hBre[8], hBim[8];

#define PREF(DRE, DIM_, BLKN) do {                                                   \
        const float* _pr = H_re + ((size_t)(BLKN) * 64 + rbase) * 1024 + hcol;       \
        const float* _pi = H_im + ((size_t)(BLKN) * 64 + rbase) * 1024 + hcol;       \
        _Pragma("unroll")                                                            \
        for (int _j = 0; _j < 8; ++_j) {                                             \
            DRE[_j]  = *(const float4*)(_pr + (size_t)_j * 8192);                    \
            DIM_[_j] = *(const float4*)(_pi + (size_t)_j * 8192);                    \
        }                                                                            \
    } while (0)

    PREF(hAre, hAim, 0);   // prologue: bank A <- block 0

#define STEP(BLK, CRE, CIM, NRE, NIM) do {                                           \
        const int blk = (BLK);                                                       \
        const int par = blk & 1;                                                     \
        const unsigned stag = (unsigned)(iter * 512 + blk + 1);                      \
        __syncthreads();   /* x_l / LDS reuse boundary */                            \
        /* ---- Phase A: partial z[b,w] over own 128-d chunk (CUR bank) ---- */      \
        float2 xr0 = x_l[sub * 4 + 0], xr1 = x_l[sub * 4 + 1];                       \
        float2 xr2 = x_l[sub * 4 + 2], xr3 = x_l[sub * 4 + 3];                       \
        _Pragma("unroll")                                                            \
        for (int j = 0; j < 8; ++j) {                                                \
            float4 hr = CRE[j], hi = CIM[j];                                         \
            float sr, si;                                                            \
            sr  = xr0.x * hr.x - xr0.y * hi.x;  si  = xr0.x * hi.x + xr0.y * hr.x;   \
            sr += xr1.x * hr.y - xr1.y * hi.y;  si += xr1.x * hi.y + xr1.y * hr.y;   \
            sr += xr2.x * hr.z - xr2.y * hi.z;  si += xr2.x * hi.z + xr2.y * hr.z;   \
            sr += xr3.x * hr.w - xr3.y * hi.w;  si += xr3.x * hi.w + xr3.y * hr.w;   \
            _Pragma("unroll")                                                        \
            for (int m = 1; m < 32; m <<= 1) {                                       \
                sr += __shfl_xor(sr, m); si += __shfl_xor(si, m);                    \
            }                                                                        \
            ull* pw = partuw + ((size_t)par * 512 + b * 64 + rbase + 8 * j) * 16     \
                             + (size_t)c * 2;                                        \
            if (sub == 0)      st_u64(pw,     pack_tf(stag, sr));                    \
            else if (sub == 1) st_u64(pw + 1, pack_tf(stag, si));                    \
        }                                                                            \
        /* ---- overlap: prefetch H(blk+1), tau(blk+1), y(blk) before polling */     \
        PREF(NRE, NIM, ((blk + 1) & 511));                                           \
        unsigned tauw = 0;                                                           \
        if (t < 64)                                                                  \
            tauw = ld_u(&tau32[(((blk + 1) & 511) * 8 + b) * 32 + (t >> 1)]);        \
        float yAr, yAi, yBr, yBi;                                                    \
        {                                                                            \
            int b1 = t >> 6, w1 = t & 63, n1 = blk * 64 + w1;                        \
            if (n1 < 16384) { yAr = y_re[b1 * 16384 + n1];         yAi = y_im[b1 * 16384 + n1]; } \
            else            { yAr = y_re[b1 * 16384 + n1 - 16384]; yAi = -y_im[b1 * 16384 + n1 - 16384]; } \
            int i2 = t + 256;                                                        \
            int b2 = i2 >> 6, w2 = i2 & 63, n2 = blk * 64 + w2;                      \
            if (n2 < 16384) { yBr = y_re[b2 * 16384 + n2];         yBi = y_im[b2 * 16384 + n2]; } \
            else            { yBr = y_re[b2 * 16384 + n2 - 16384]; yBi = -y_im[b2 * 16384 + n2 - 16384]; } \
        }                                                                            \
        /* ---- Phase B: poll tagged partials (single producer->consumer hop) */     \
        _Pragma("unroll")                                                            \
        for (int e = 0; e < 2; ++e) {                                                \
            int idx = t + e * 256;                                                   \
            const ull* pb = partuw + ((size_t)par * 512 + idx) * 16;                 \
            float zr = 0.0f, zi = 0.0f;                                              \
            _Pragma("unroll")                                                        \
            for (int h = 0; h < 2; ++h) {                                            \
                const ull* pc = pb + h * 8;                                          \
                ull v0, v1, v2, v3, v4, v5, v6, v7;                                  \
                bool ok = false;                                                     \
                while (!ok) {                                                        \
                    v0 = ld_u64(pc + 0); v1 = ld_u64(pc + 1);                        \
                    v2 = ld_u64(pc + 2); v3 = ld_u64(pc + 3);                        \
                    v4 = ld_u64(pc + 4); v5 = ld_u64(pc + 5);                        \
                    v6 = ld_u64(pc + 6); v7 = ld_u64(pc + 7);                        \
                    ok = ((unsigned)v0 == stag) & ((unsigned)v1 == stag)             \
                       & ((unsigned)v2 == stag) & ((unsigned)v3 == stag)             \
                       & ((unsigned)v4 == stag) & ((unsigned)v5 == stag)             \
                       & ((unsigned)v6 == stag) & ((unsigned)v7 == stag);            \
                    if (!ok) __builtin_amdgcn_s_sleep(1);                            \
                }                                                                    \
                zr += hi_f(v0) + hi_f(v2) + hi_f(v4) + hi_f(v6);                     \
                zi += hi_f(v1) + hi_f(v3) + hi_f(v5) + hi_f(v7);                     \
            }                                                                        \
            float rr = ((e == 0) ? yAr : yBr) - zr;                                  \
            float ri = ((e == 0) ? yAi : yBi) - zi;                                  \
            a2s[idx] = rr * rr + ri * ri;                                            \
            int b1 = idx >> 6, w = idx & 63;                                         \
            if (b1 == b) rown[w] = make_float2(rr, ri);                              \
        }                                                                            \
        __syncthreads();                                                             \
        /* ---- std(global, ddof=1), sigma2(b) ---- */                               \
        float va = a2s[t] + a2s[t + 256];                                            \
        float s_ = wsum64(va);                                                       \
        if (lane == 0) redl[wv] = s_;                                                \
        __syncthreads();                                                             \
        float mean = (redl[0] + redl[1] + redl[2] + redl[3]) * (1.0f / 512.0f);      \
        float d0 = a2s[t] - mean, d1 = a2s[t + 256] - mean;                          \
        float s2_ = wsum64(d0 * d0 + d1 * d1);                                       \
        float sg  = wsum64(a2s[b * 64 + lane]) * (1.0f / 64.0f);                     \
        if (lane == 0) redl[4 + wv] = s2_;                                           \
        __syncthreads();                                                             \
        float stdv = sqrtf((redl[4] + redl[5] + redl[6] + redl[7]) * (1.0f / 511.0f)); \
        if (t < 64) xts[t] = a2s[b * 64 + t] / stdv;                                 \
        __syncthreads();                                                             \
        /* ---- MLP layer 1: 256-thread 4-way k-split ---- */                        \
        {                                                                            \
            int j = t & 63, q = t >> 6;                                              \
            float acc = 0.0f;                                                        \
            _Pragma("unroll")                                                        \
            for (int k16 = 0; k16 < 16; ++k16) {                                     \
                int k = q * 16 + k16;                                                \
                acc += wTe[k * 64 + j] * xts[k];                                     \
            }                                                                        \
            mpartf[q * 64 + j] = acc;                                                \
        }                                                                            \
        __syncthreads();                                                             \
        if (t < 64) {                                                                \
            float acc = be[t] + mpartf[t] + mpartf[64 + t] + mpartf[128 + t] + mpartf[192 + t]; \
            hts[t] = 1.0f / (1.0f + expf(-acc));                                     \
        }                                                                            \
        __syncthreads();                                                             \
        /* ---- MLP layer 2: update + memory, 4-way k-split ---- */                  \
        {                                                                            \
            int j = t & 63, q = t >> 6;                                              \
            float acc = 0.0f;                                                        \
            _Pragma("unroll")                                                        \
            for (int k16 = 0; k16 < 16; ++k16) {                                     \
                int k = q * 16 + k16;                                                \
                acc += wTu[k * 64 + j] * hts[k] + wTm[k * 64 + j] * taurow[k];       \
            }                                                                        \
            mpartf[q * 64 + j] = acc;                                                \
        }                                                                            \
        __syncthreads();                                                             \
        if (t < 64) {                                                                \
            float tn = bu[t] + bm[t] + mpartf[t] + mpartf[64 + t] + mpartf[128 + t] + mpartf[192 + t]; \
            tn = fmaxf(tn, 0.0f);                                                    \
            float tno = __shfl_xor(tn, 1);                                           \
            if (c == 0 && (t & 1) == 0)                                              \
                st_u(&tau32[(blk * 8 + b) * 32 + (t >> 1)], bf16pack(tn, tno));      \
            float2 rv = rown[t];                                                     \
            float scl = tn / sg;                                                     \
            resid[t] = make_float2(rv.x * scl, rv.y * scl);                          \
        }                                                                            \
        __syncthreads();                                                             \
        /* ---- Phase C: x[b, own chunk] += resid @ conj(H) / 65536 (CUR bank) */    \
        float2 ac0 = make_float2(0.f, 0.f), ac1 = make_float2(0.f, 0.f);             \
        float2 ac2 = make_float2(0.f, 0.f), ac3 = make_float2(0.f, 0.f);             \
        _Pragma("unroll")                                                            \
        for (int j = 0; j < 8; ++j) {                                                \
            float2 rs = resid[rbase + 8 * j];                                        \
            float4 hr = CRE[j], hi = CIM[j];                                         \
            ac0.x += rs.x * hr.x + rs.y * hi.x;  ac0.y += rs.y * hr.x - rs.x * hi.x; \
            ac1.x += rs.x * hr.y + rs.y * hi.y;  ac1.y += rs.y * hr.y - rs.x * hi.y; \
            ac2.x += rs.x * hr.z + rs.y * hi.z;  ac2.y += rs.y * hr.z - rs.x * hi.z; \
            ac3.x += rs.x * hr.w + rs.y * hi.w;  ac3.y += rs.y * hr.w - rs.x * hi.w; \
        }                                                                            \
        ac0.x += __shfl_xor(ac0.x, 32); ac0.y += __shfl_xor(ac0.y, 32);              \
        ac1.x += __shfl_xor(ac1.x, 32); ac1.y += __shfl_xor(ac1.y, 32);              \
        ac2.x += __shfl_xor(ac2.x, 32); ac2.y += __shfl_xor(ac2.y, 32);              \
        ac3.x += __shfl_xor(ac3.x, 32); ac3.y += __shfl_xor(ac3.y, 32);              \
        if ((t & 32) == 0) {                                                         \
            cpartC[wv][sub][0] = ac0; cpartC[wv][sub][1] = ac1;                      \
            cpartC[wv][sub][2] = ac2; cpartC[wv][sub][3] = ac3;                      \
        }                                                                            \
        if (t < 64)   /* commit prefetched tau (bf16 -> f32) */                      \
            taurow[t] = (t & 1) ? bf16hi(tauw) : bf16lo(tauw);                       \
        __syncthreads();                                                             \
        if (t < 128) {                                                               \
            int sl = t >> 2, kk = t & 3;                                             \
            float2 s0 = cpartC[0][sl][kk], s1 = cpartC[1][sl][kk];                   \
            float2 s2 = cpartC[2][sl][kk], s3 = cpartC[3][sl][kk];                   \
            float2 xv = x_l[t];                                                      \
            xv.x += (s0.x + s1.x + s2.x + s3.x) * (1.0f / 65536.0f);                 \
            xv.y += (s0.y + s1.y + s2.y + s3.y) * (1.0f / 65536.0f);                 \
            x_l[t] = xv;                                                             \
        }                                                                            \
    } while (0)

    #pragma unroll 1
    for (int iter = 0; iter < 10; ++iter) {
        #pragma unroll 1
        for (int blk2 = 0; blk2 < 512; blk2 += 2) {
            STEP(blk2,     hAre, hAim, hBre, hBim);
            STEP(blk2 + 1, hBre, hBim, hAre, hAim);
        }

        // ---- soft threshold: x = sgn(x) * relu(|x| - 1e-3 * max|x| (global)) ----
        float lm = 0.0f;
        if (t < 128) { float2 xv = x_l[t]; lm = sqrtf(xv.x * xv.x + xv.y * xv.y); }
        lm = wmax64(lm);
        if (lane == 0) redl[wv] = lm;
        __syncthreads();
        if (t == 0) st_f(&pmws[g], fmaxf(fmaxf(redl[0], redl[1]), fmaxf(redl[2], redl[3])));
        ++ep;
        {
            unsigned* plane = flags + ((ep & 1u) << 9);
            __syncthreads();                     // drain pm (and this WG's tau) stores
            if (t == 0) st_u(&plane[g * 8], ep);
            if (t < 64) {
                while (ld_u(&plane[t * 8]) != ep) __builtin_amdgcn_s_sleep(1);
            }
            __syncthreads();
        }
        float pv = (t < 64) ? ld_f(&pmws[t]) : 0.0f;
        pv = wmax64(pv);
        if (t == 0) gmax[0] = pv;
        __syncthreads();
        float m = gmax[0];
        if (t < 128) {
            float2 xv = x_l[t];
            float ax = sqrtf(xv.x * xv.x + xv.y * xv.y);
            float s = (ax > 0.0f) ? fmaxf(ax - 1e-3f * m, 0.0f) / ax : 0.0f;
            x_l[t] = make_float2(xv.x * s, xv.y * s);
        }
        __syncthreads();
    } // iter

    // ---------------- output ----------------
    if (t < 128) out[b * 1024 + c * 128 + t] = x_l[t].x;
    for (int i = g * 8; i < g * 8 + 8; ++i) {
        for (int idx = t; idx < 512; idx += NT) {
            int bb = idx >> 6, w = idx & 63;
            unsigned uw = ld_u(&tau32[(i * 8 + bb) * 32 + (w >> 1)]);
            out[8192 + bb * 32768 + i * 64 + w] = (w & 1) ? bf16hi(uw) : bf16lo(uw);
        }
    }
#undef STEP
#undef PREF
}

// Diagnostic: if the launch is rejected, stamp the error code into output-0
// as code-distinguishable-through-bf16 multiples of 1e6.
__global__ void robii_diag_kernel(float* out, int code) {
    int i = blockIdx.x * blockDim.x + threadIdx.x;
    if (i < 8192) out[i] = 1.0e6f * (float)(1 + code);
}

extern "C" void kernel_launch(void* const* d_in, const int* in_sizes, int n_in,
                              void* d_out, int out_size, void* d_ws, size_t ws_size,
                              hipStream_t stream) {
    (void)in_sizes; (void)n_in; (void)out_size; (void)ws_size;
    const float* y_re     = (const float*)d_in[0];
    const float* y_im     = (const float*)d_in[1];
    const float* H_re     = (const float*)d_in[2];
    const float* H_im     = (const float*)d_in[3];
    const float* estep_w  = (const float*)d_in[4];
    const float* estep_b  = (const float*)d_in[5];
    const float* update_w = (const float*)d_in[6];
    const float* update_b = (const float*)d_in[7];
    const float* memory_w = (const float*)d_in[8];
    const float* memory_b = (const float*)d_in[9];
    float* outp = (float*)d_out;
    float* wsp  = (float*)d_ws;

    // plain (non-cooperative) launch — 64 blocks on 256 CUs always co-resident
    hipLaunchKernelGGL(robii_kernel, dim3(NWG), dim3(NT), 0, stream,
                       y_re, y_im, H_re, H_im, estep_w, estep_b,
                       update_w, update_b, memory_w, memory_b, outp, wsp);
    hipError_t e = hipGetLastError();
    if (e != hipSuccess) {
        hipLaunchKernelGGL(robii_diag_kernel, dim3(32), dim3(256), 0, stream,
                           outp, (int)e);
    }
}

// Round 12
// 37741.037 us; speedup vs baseline: 1.6231x; 1.6231x over previous
//
#include <hip/hip_runtime.h>
#include <math.h>

#define NT  256
#define NWG 64
#define SCOPE_AG __HIP_MEMORY_SCOPE_AGENT
typedef unsigned long long ull;

// ---------- agent-scope (coherence-point) atomic helpers ----------
__device__ __forceinline__ float ld_f(const float* p) {
    return __hip_atomic_load(p, __ATOMIC_RELAXED, SCOPE_AG);
}
__device__ __forceinline__ void st_f(float* p, float v) {
    __hip_atomic_store(p, v, __ATOMIC_RELAXED, SCOPE_AG);
}
__device__ __forceinline__ unsigned ld_u(const unsigned* p) {
    return __hip_atomic_load(p, __ATOMIC_RELAXED, SCOPE_AG);
}
__device__ __forceinline__ void st_u(unsigned* p, unsigned v) {
    __hip_atomic_store(p, v, __ATOMIC_RELAXED, SCOPE_AG);
}
__device__ __forceinline__ void st_u_rel(unsigned* p, unsigned v) {
    __hip_atomic_store(p, v, __ATOMIC_RELEASE, SCOPE_AG);
}
__device__ __forceinline__ ull ld_u64(const ull* p) {
    return __hip_atomic_load(p, __ATOMIC_RELAXED, SCOPE_AG);
}
__device__ __forceinline__ void st_u64(ull* p, ull v) {
    __hip_atomic_store(p, v, __ATOMIC_RELAXED, SCOPE_AG);
}

// mantissa tag: low 8 bits of the float carry the epoch tag (noise ~2^-17 rel)
__device__ __forceinline__ unsigned tagf(float v, unsigned tg) {
    return (__float_as_uint(v) & 0xFFFFFF00u) | tg;
}
__device__ __forceinline__ ull pack2(float lo, float hi, unsigned tg) {
    return ((ull)tagf(hi, tg) << 32) | (ull)tagf(lo, tg);
}

__device__ __forceinline__ float wsum64(float v) {
    #pragma unroll
    for (int m = 1; m < 64; m <<= 1) v += __shfl_xor(v, m);
    return v;
}
__device__ __forceinline__ float wmax64(float v) {
    #pragma unroll
    for (int m = 1; m < 64; m <<= 1) v = fmaxf(v, __shfl_xor(v, m));
    return v;
}

// ws layout (floats) — total 278,592 floats = 1,114,368 B (under proven cap):
//   partuw: ull[2 par][512 (b,w)][8 c]   @ 0       (16384 floats)
//           each u64 = two mantissa-tagged floats (re lo, im hi)
//           tag = (iter*512+blk+1) & 0xFF
//   tauws:  float[512 blk][8 b][64 w]    @ 16384   (262144 floats)
//   pm_u:   unsigned[64]                 @ 278528  (tagged floats; tag=iter+1, init=255)
//
// Protocol: consumers poll partial words until BOTH halves carry the step tag.
// 2-parity bounded-lead => a buffer always holds tag s or s-2 (never ==s early);
// cross-replay stale tags 127/128 vs first polls 1/2; 0xAA poison != 1/2.

__launch_bounds__(NT, 1)
__global__ void robii_kernel(
    const float* __restrict__ y_re, const float* __restrict__ y_im,
    const float* __restrict__ H_re, const float* __restrict__ H_im,
    const float* __restrict__ estep_w, const float* __restrict__ estep_b,
    const float* __restrict__ update_w, const float* __restrict__ update_b,
    const float* __restrict__ memory_w, const float* __restrict__ memory_b,
    float* __restrict__ out, float* __restrict__ ws)
{
    __shared__ float wTe[4096], wTu[4096], wTm[4096];  // transposed: wT[k*64+j] = w[j][k]
    __shared__ float be[64], bu[64], bm[64];
    __shared__ float a2s[512];
    __shared__ float redl[8];
    __shared__ float gmax[1];
    __shared__ float2 rown[64];
    __shared__ float xts[64], hts[64], taurow[64];
    __shared__ float2 resid[64];
    __shared__ float2 cpartC[4][32][4];   // Phase-C scratch; aliased as MLP partials
    __shared__ float2 x_l[128];     // this WG's x[b, c*128 .. c*128+127]

    float* mpartf = (float*)cpartC;  // [4][64] floats (time-shared with Phase C)

    const int g = blockIdx.x, t = threadIdx.x;
    const int c = g & 7;        // d-chunk owned
    const int b = g >> 3;       // batch owned
    const int lane = t & 63, wv = t >> 6;
    const int sub = t & 31;     // column slice (4 floats)
    const int rbase = t >> 5;   // row group 0..7 (rows rbase+8j)

    ull*      partuw = (ull*)ws;                 // [2][512][8] u64
    float*    tauws  = ws + 16384;               // [512][8][64]
    unsigned* pm_u   = (unsigned*)(ws + 278528); // [64] tagged floats

    // ---------------- init ----------------
    for (int i = t; i < 4096; i += NT) {
        int j = i >> 6, k = i & 63;
        wTe[k * 64 + j] = estep_w[i];
        wTu[k * 64 + j] = update_w[i];
        wTm[k * 64 + j] = memory_w[i];
    }
    if (t < 64) { be[t] = estep_b[t]; bu[t] = update_b[t]; bm[t] = memory_b[t]; taurow[t] = 1.0f; }
    if (t < 128) x_l[t] = make_float2(0.0f, 0.0f);
    for (int i = t; i < 4096; i += NT) st_f(&tauws[g * 4096 + i], 1.0f);

    // init sync via tagged pm (tag 255): publishes tau init.
    __syncthreads();                              // drains this WG's tau stores
    if (t == 0) st_u_rel(&pm_u[g], tagf(1.0f, 255u));
    if (t < 64) {
        while ((ld_u(&pm_u[t]) & 0xFFu) != 255u) __builtin_amdgcn_s_sleep(1);
    }
    __builtin_amdgcn_fence(__ATOMIC_ACQUIRE, "agent");
    __syncthreads();

    const size_t hcol = (size_t)c * 128 + (size_t)sub * 4;

    // H double-buffer register banks
    float4 hAre[8], hAim[8], hBre[8], hBim[8];

#define PREF(DRE, DIM_, BLKN) do {                                                   \
        const float* _pr = H_re + ((size_t)(BLKN) * 64 + rbase) * 1024 + hcol;       \
        const float* _pi = H_im + ((size_t)(BLKN) * 64 + rbase) * 1024 + hcol;       \
        _Pragma("unroll")                                                            \
        for (int _j = 0; _j < 8; ++_j) {                                             \
            DRE[_j]  = *(const float4*)(_pr + (size_t)_j * 8192);                    \
            DIM_[_j] = *(const float4*)(_pi + (size_t)_j * 8192);                    \
        }                                                                            \
    } while (0)

    PREF(hAre, hAim, 0);   // prologue: bank A <- block 0

#define STEP(BLK, CRE, CIM, NRE, NIM) do {                                           \
        const int blk = (BLK);                                                       \
        const int par = blk & 1;                                                     \
        const unsigned tg = (unsigned)(iter * 512 + blk + 1) & 0xFFu;                \
        __syncthreads();   /* x_l / LDS reuse boundary */                            \
        /* ---- Phase A: partial z[b,w] over own 128-d chunk (H from CUR bank), */   \
        /* stores carry the step tag in each float's low mantissa byte ---- */       \
        float2 xr0 = x_l[sub * 4 + 0], xr1 = x_l[sub * 4 + 1];                       \
        float2 xr2 = x_l[sub * 4 + 2], xr3 = x_l[sub * 4 + 3];                       \
        _Pragma("unroll")                                                            \
        for (int j = 0; j < 8; ++j) {                                                \
            float4 hr = CRE[j], hi = CIM[j];                                         \
            float sr, si;                                                            \
            sr  = xr0.x * hr.x - xr0.y * hi.x;  si  = xr0.x * hi.x + xr0.y * hr.x;   \
            sr += xr1.x * hr.y - xr1.y * hi.y;  si += xr1.x * hi.y + xr1.y * hr.y;   \
            sr += xr2.x * hr.z - xr2.y * hi.z;  si += xr2.x * hi.z + xr2.y * hr.z;   \
            sr += xr3.x * hr.w - xr3.y * hi.w;  si += xr3.x * hi.w + xr3.y * hr.w;   \
            _Pragma("unroll")                                                        \
            for (int m = 1; m < 32; m <<= 1) {                                       \
                sr += __shfl_xor(sr, m); si += __shfl_xor(si, m);                    \
            }                                                                        \
            if (sub == 0)                                                            \
                st_u64(&partuw[(size_t)par * 4096 + (b * 64 + rbase + 8 * j) * 8 + c], \
                       pack2(sr, si, tg));                                           \
        }                                                                            \
        /* ---- overlap: prefetch H(blk+1) + tau(blk+1) + y(blk) ---- */             \
        PREF(NRE, NIM, ((blk + 1) & 511));                                           \
        float tau_nxt = 0.0f;                                                        \
        if (t < 64) tau_nxt = ld_f(&tauws[(((blk + 1) & 511) * 8 + b) * 64 + t]);    \
        float yAr, yAi, yBr, yBi;                                                    \
        {                                                                            \
            int b1 = t >> 6, w1 = t & 63, n1 = blk * 64 + w1;                        \
            if (n1 < 16384) { yAr = y_re[b1 * 16384 + n1];         yAi = y_im[b1 * 16384 + n1]; } \
            else            { yAr = y_re[b1 * 16384 + n1 - 16384]; yAi = -y_im[b1 * 16384 + n1 - 16384]; } \
            int i2 = t + 256;                                                        \
            int b2 = i2 >> 6, w2 = i2 & 63, n2 = blk * 64 + w2;                      \
            if (n2 < 16384) { yBr = y_re[b2 * 16384 + n2];         yBi = y_im[b2 * 16384 + n2]; } \
            else            { yBr = y_re[b2 * 16384 + n2 - 16384]; yBi = -y_im[b2 * 16384 + n2 - 16384]; } \
        }                                                                            \
        /* ---- Phase B: poll tagged partials (flag==data, zero extra bytes) ---- */ \
        _Pragma("unroll")                                                            \
        for (int e = 0; e < 2; ++e) {                                                \
            int idx = t + e * 256;                                                   \
            const ull* pb = partuw + (size_t)par * 4096 + (size_t)idx * 8;           \
            ull v0, v1, v2, v3, v4, v5, v6, v7;                                      \
            bool ok = false;                                                         \
            while (!ok) {                                                            \
                v0 = ld_u64(pb + 0); v1 = ld_u64(pb + 1);                            \
                v2 = ld_u64(pb + 2); v3 = ld_u64(pb + 3);                            \
                v4 = ld_u64(pb + 4); v5 = ld_u64(pb + 5);                            \
                v6 = ld_u64(pb + 6); v7 = ld_u64(pb + 7);                            \
                unsigned m01 = ((unsigned)v0 & 0xFFu) ^ tg;                          \
                m01 |= ((unsigned)(v0 >> 32) & 0xFFu) ^ tg;                          \
                m01 |= ((unsigned)v1 & 0xFFu) ^ tg;                                  \
                m01 |= ((unsigned)(v1 >> 32) & 0xFFu) ^ tg;                          \
                m01 |= ((unsigned)v2 & 0xFFu) ^ tg;                                  \
                m01 |= ((unsigned)(v2 >> 32) & 0xFFu) ^ tg;                          \
                m01 |= ((unsigned)v3 & 0xFFu) ^ tg;                                  \
                m01 |= ((unsigned)(v3 >> 32) & 0xFFu) ^ tg;                          \
                m01 |= ((unsigned)v4 & 0xFFu) ^ tg;                                  \
                m01 |= ((unsigned)(v4 >> 32) & 0xFFu) ^ tg;                          \
                m01 |= ((unsigned)v5 & 0xFFu) ^ tg;                                  \
                m01 |= ((unsigned)(v5 >> 32) & 0xFFu) ^ tg;                          \
                m01 |= ((unsigned)v6 & 0xFFu) ^ tg;                                  \
                m01 |= ((unsigned)(v6 >> 32) & 0xFFu) ^ tg;                          \
                m01 |= ((unsigned)v7 & 0xFFu) ^ tg;                                  \
                m01 |= ((unsigned)(v7 >> 32) & 0xFFu) ^ tg;                          \
                ok = (m01 == 0u);                                                    \
                if (!ok) __builtin_amdgcn_s_sleep(1);                                \
            }                                                                        \
            float zr = __uint_as_float((unsigned)v0) + __uint_as_float((unsigned)v1) \
                     + __uint_as_float((unsigned)v2) + __uint_as_float((unsigned)v3) \
                     + __uint_as_float((unsigned)v4) + __uint_as_float((unsigned)v5) \
                     + __uint_as_float((unsigned)v6) + __uint_as_float((unsigned)v7);\
            float zi = __uint_as_float((unsigned)(v0 >> 32)) + __uint_as_float((unsigned)(v1 >> 32)) \
                     + __uint_as_float((unsigned)(v2 >> 32)) + __uint_as_float((unsigned)(v3 >> 32)) \
                     + __uint_as_float((unsigned)(v4 >> 32)) + __uint_as_float((unsigned)(v5 >> 32)) \
                     + __uint_as_float((unsigned)(v6 >> 32)) + __uint_as_float((unsigned)(v7 >> 32));\
            float rr = ((e == 0) ? yAr : yBr) - zr;                                  \
            float ri = ((e == 0) ? yAi : yBi) - zi;                                  \
            a2s[idx] = rr * rr + ri * ri;                                            \
            int b1 = idx >> 6, w = idx & 63;                                         \
            if (b1 == b) rown[w] = make_float2(rr, ri);                              \
        }                                                                            \
        __syncthreads();                                                             \
        /* ---- std(global, ddof=1), sigma2(b) ---- */                               \
        float va = a2s[t] + a2s[t + 256];                                            \
        float s_ = wsum64(va);                                                       \
        if (lane == 0) redl[wv] = s_;                                                \
        __syncthreads();                                                             \
        float mean = (redl[0] + redl[1] + redl[2] + redl[3]) * (1.0f / 512.0f);      \
        float d0 = a2s[t] - mean, d1 = a2s[t + 256] - mean;                          \
        float s2_ = wsum64(d0 * d0 + d1 * d1);                                       \
        float sg  = wsum64(a2s[b * 64 + lane]) * (1.0f / 64.0f);                     \
        if (lane == 0) redl[4 + wv] = s2_;                                           \
        __syncthreads();                                                             \
        float stdv = sqrtf((redl[4] + redl[5] + redl[6] + redl[7]) * (1.0f / 511.0f)); \
        if (t < 64) xts[t] = a2s[b * 64 + t] / stdv;                                 \
        __syncthreads();                                                             \
        /* ---- MLP layer 1: 256-thread 4-way k-split ---- */                        \
        {                                                                            \
            int j = t & 63, q = t >> 6;                                              \
            float acc = 0.0f;                                                        \
            _Pragma("unroll")                                                        \
            for (int k16 = 0; k16 < 16; ++k16) {                                     \
                int k = q * 16 + k16;                                                \
                acc += wTe[k * 64 + j] * xts[k];                                     \
            }                                                                        \
            mpartf[q * 64 + j] = acc;                                                \
        }                                                                            \
        __syncthreads();                                                             \
        if (t < 64) {                                                                \
            float acc = be[t] + mpartf[t] + mpartf[64 + t] + mpartf[128 + t] + mpartf[192 + t]; \
            hts[t] = 1.0f / (1.0f + expf(-acc));                                     \
        }                                                                            \
        __syncthreads();                                                             \
        /* ---- MLP layer 2: update + memory, 4-way k-split ---- */                  \
        {                                                                            \
            int j = t & 63, q = t >> 6;                                              \
            float acc = 0.0f;                                                        \
            _Pragma("unroll")                                                        \
            for (int k16 = 0; k16 < 16; ++k16) {                                     \
                int k = q * 16 + k16;                                                \
                acc += wTu[k * 64 + j] * hts[k] + wTm[k * 64 + j] * taurow[k];       \
            }                                                                        \
            mpartf[q * 64 + j] = acc;                                                \
        }                                                                            \
        __syncthreads();                                                             \
        if (t < 64) {                                                                \
            float tn = bu[t] + bm[t] + mpartf[t] + mpartf[64 + t] + mpartf[128 + t] + mpartf[192 + t]; \
            tn = fmaxf(tn, 0.0f);                                                    \
            if (c == 0) st_f(&tauws[(blk * 8 + b) * 64 + t], tn);                    \
            float2 rv = rown[t];                                                     \
            float scl = tn / sg;                                                     \
            resid[t] = make_float2(rv.x * scl, rv.y * scl);                          \
        }                                                                            \
        __syncthreads();                                                             \
        /* ---- Phase C: x[b, own chunk] += resid @ conj(H) / 65536 (CUR bank) */    \
        float2 ac0 = make_float2(0.f, 0.f), ac1 = make_float2(0.f, 0.f);             \
        float2 ac2 = make_float2(0.f, 0.f), ac3 = make_float2(0.f, 0.f);             \
        _Pragma("unroll")                                                            \
        for (int j = 0; j < 8; ++j) {                                                \
            float2 rs = resid[rbase + 8 * j];                                        \
            float4 hr = CRE[j], hi = CIM[j];                                         \
            ac0.x += rs.x * hr.x + rs.y * hi.x;  ac0.y += rs.y * hr.x - rs.x * hi.x; \
            ac1.x += rs.x * hr.y + rs.y * hi.y;  ac1.y += rs.y * hr.y - rs.x * hi.y; \
            ac2.x += rs.x * hr.z + rs.y * hi.z;  ac2.y += rs.y * hr.z - rs.x * hi.z; \
            ac3.x += rs.x * hr.w + rs.y * hi.w;  ac3.y += rs.y * hr.w - rs.x * hi.w; \
        }                                                                            \
        ac0.x += __shfl_xor(ac0.x, 32); ac0.y += __shfl_xor(ac0.y, 32);              \
        ac1.x += __shfl_xor(ac1.x, 32); ac1.y += __shfl_xor(ac1.y, 32);              \
        ac2.x += __shfl_xor(ac2.x, 32); ac2.y += __shfl_xor(ac2.y, 32);              \
        ac3.x += __shfl_xor(ac3.x, 32); ac3.y += __shfl_xor(ac3.y, 32);              \
        if ((t & 32) == 0) {                                                         \
            cpartC[wv][sub][0] = ac0; cpartC[wv][sub][1] = ac1;                      \
            cpartC[wv][sub][2] = ac2; cpartC[wv][sub][3] = ac3;                      \
        }                                                                            \
        if (t < 64) taurow[t] = tau_nxt;       /* commit prefetched tau */           \
        __syncthreads();                                                             \
        if (t < 128) {                                                               \
            int sl = t >> 2, kk = t & 3;                                             \
            float2 s0 = cpartC[0][sl][kk], s1 = cpartC[1][sl][kk];                   \
            float2 s2 = cpartC[2][sl][kk], s3 = cpartC[3][sl][kk];                   \
            float2 xv = x_l[t];                                                      \
            xv.x += (s0.x + s1.x + s2.x + s3.x) * (1.0f / 65536.0f);                 \
            xv.y += (s0.y + s1.y + s2.y + s3.y) * (1.0f / 65536.0f);                 \
            x_l[t] = xv;                                                             \
        }                                                                            \
    } while (0)

    #pragma unroll 1
    for (int iter = 0; iter < 10; ++iter) {
        #pragma unroll 1
        for (int blk2 = 0; blk2 < 512; blk2 += 2) {
            STEP(blk2,     hAre, hAim, hBre, hBim);
            STEP(blk2 + 1, hBre, hBim, hAre, hAim);
        }

        // ---- soft threshold: x = sgn(x) * relu(|x| - 1e-3 * max|x| (global)) ----
        const unsigned itg = (unsigned)(iter + 1);   // 1..10 (never 255/0xAA)
        float lm = 0.0f;
        if (t < 128) { float2 xv = x_l[t]; lm = sqrtf(xv.x * xv.x + xv.y * xv.y); }
        lm = wmax64(lm);
        if (lane == 0) redl[wv] = lm;
        __syncthreads();   // redl ready; also drains this WG's tau stores
        if (t == 0)
            st_u_rel(&pm_u[g], tagf(fmaxf(fmaxf(redl[0], redl[1]), fmaxf(redl[2], redl[3])), itg));
        float pv = 0.0f;
        if (t < 64) {
            unsigned u;
            for (;;) {
                u = ld_u(&pm_u[t]);
                if ((u & 0xFFu) == itg) break;
                __builtin_amdgcn_s_sleep(1);
            }
            pv = __uint_as_float(u);
        }
        __builtin_amdgcn_fence(__ATOMIC_ACQUIRE, "agent");
        pv = wmax64(pv);
        if (t == 0) gmax[0] = pv;
        __syncthreads();
        float m = gmax[0];
        if (t < 128) {
            float2 xv = x_l[t];
            float ax = sqrtf(xv.x * xv.x + xv.y * xv.y);
            float s = (ax > 0.0f) ? fmaxf(ax - 1e-3f * m, 0.0f) / ax : 0.0f;
            x_l[t] = make_float2(xv.x * s, xv.y * s);
        }
        __syncthreads();
    } // iter

    // ---------------- output ----------------
    // (final pm poll at iter 9 + acquire fence orders all WGs' tau writes
    //  before these reads)
    if (t < 128) out[b * 1024 + c * 128 + t] = x_l[t].x;
    for (int i = g * 8; i < g * 8 + 8; ++i) {
        for (int idx = t; idx < 512; idx += NT) {
            int bb = idx >> 6, w = idx & 63;
            out[8192 + bb * 32768 + i * 64 + w] = ld_f(&tauws[(i * 8 + bb) * 64 + w]);
        }
    }
#undef STEP
#undef PREF
}

// Diagnostic: if the launch is rejected, stamp the error code into output-0
// as code-distinguishable-through-bf16 multiples of 1e6.
__global__ void robii_diag_kernel(float* out, int code) {
    int i = blockIdx.x * blockDim.x + threadIdx.x;
    if (i < 8192) out[i] = 1.0e6f * (float)(1 + code);
}

extern "C" void kernel_launch(void* const* d_in, const int* in_sizes, int n_in,
                              void* d_out, int out_size, void* d_ws, size_t ws_size,
                              hipStream_t stream) {
    (void)in_sizes; (void)n_in; (void)out_size; (void)ws_size;
    const float* y_re     = (const float*)d_in[0];
    const float* y_im     = (const float*)d_in[1];
    const float* H_re     = (const float*)d_in[2];
    const float* H_im     = (const float*)d_in[3];
    const float* estep_w  = (const float*)d_in[4];
    const float* estep_b  = (const float*)d_in[5];
    const float* update_w = (const float*)d_in[6];
    const float* update_b = (const float*)d_in[7];
    const float* memory_w = (const float*)d_in[8];
    const float* memory_b = (const float*)d_in[9];
    float* outp = (float*)d_out;
    float* wsp  = (float*)d_ws;

    // plain (non-cooperative) launch — 64 blocks on 256 CUs always co-resident
    hipLaunchKernelGGL(robii_kernel, dim3(NWG), dim3(NT), 0, stream,
                       y_re, y_im, H_re, H_im, estep_w, estep_b,
                       update_w, update_b, memory_w, memory_b, outp, wsp);
    hipError_t e = hipGetLastError();
    if (e != hipSuccess) {
        hipLaunchKernelGGL(robii_diag_kernel, dim3(32), dim3(256), 0, stream,
                           outp, (int)e);
    }
}